// Round 1
// baseline (270.783 us; speedup 1.0000x reference)
//
#include <hip/hip_runtime.h>

typedef _Float16 half8 __attribute__((ext_vector_type(8)));
typedef float floatx4 __attribute__((ext_vector_type(4)));

#define IMG   3136      // 56*56
#define PIMG  3364      // 58*58
#define XP_ELEMS (32 * 58 * 58 * 128)   // 13,778,944 fp16
#define WQ_ELEMS (9 * 256 * 128)        // 294,912 fp16

// ---------------- pre-pass: x NCHW fp32 -> zero-padded NHWC fp16 ----------------
__global__ void pad_x_kernel(const float* __restrict__ x, _Float16* __restrict__ xp) {
    int t = blockIdx.x * 256 + threadIdx.x;     // exact: 53824 * 256 = XP_ELEMS
    int c  = t & 127;
    int p  = t >> 7;            // n*3364 + hh*58 + ww
    int ww = p % 58;
    int q  = p / 58;
    int hh = q % 58;
    int n  = q / 58;
    float v = 0.0f;
    if ((unsigned)(hh - 1) < 56u && (unsigned)(ww - 1) < 56u)
        v = x[((n * 128 + c) * 56 + (hh - 1)) * 56 + (ww - 1)];
    xp[t] = (_Float16)v;
}

// ---------------- pre-pass: W[k][c][r][s] fp32 -> round(W*128) fp16 [rs][k][c] ----------------
__global__ void quant_w_kernel(const float* __restrict__ W, _Float16* __restrict__ wq) {
    int t = blockIdx.x * 256 + threadIdx.x;     // exact: 1152 * 256 = WQ_ELEMS
    int c  = t & 127;
    int k  = (t >> 7) & 255;
    int rs = t >> 15;
    wq[t] = (_Float16)rintf(W[(k * 128 + c) * 9 + rs] * 128.0f);
}

// ---------------- main: implicit GEMM, M=filters(256), N=pixels(100352), K=1152 ----------------
// block: 256 thr (4 waves, 2x2), tile 128x128, BK=32, mfma 16x16x32 f16
__global__ __launch_bounds__(256) void conv_mfma_kernel(
    const _Float16* __restrict__ xp, const _Float16* __restrict__ wq,
    const float* __restrict__ b, float* __restrict__ out)
{
    __shared__ __align__(16) _Float16 smem[8192];   // A: [0,4096) halves, B: [4096,8192)
    _Float16* As = smem;            // [128 filt rows][32 c] 64B rows
    _Float16* Bs = smem + 4096;     // [128 pix rows][32 c]

    const int tid = threadIdx.x;
    const int l   = tid & 63;
    const int wv  = tid >> 6;
    const int wm  = wv & 1;         // filter half of tile
    const int wn  = wv >> 1;        // pixel half of tile
    const int bx  = blockIdx.x;     // pixel tile 0..783
    const int by  = blockIdx.y;     // filter tile 0..1

    // staging-lane decode: issue q covers rows q*64 + wv*16 + (l>>2), c-sub (l&3)*8
    const int lrow = l >> 2;
    const int lcol = (l & 3) * 8;

    // A (weights) element offsets
    const int kf0   = by * 128 + wv * 16 + lrow;
    const int aoff0 = kf0 * 128 + lcol;
    const int aoff1 = aoff0 + 64 * 128;

    // B (pixels): decode pixel -> padded-buffer base offset
    const int pix0 = bx * 128 + wv * 16 + lrow;
    const int pix1 = pix0 + 64;
    const int n0 = pix0 / IMG, hw0 = pix0 % IMG;
    const int n1 = pix1 / IMG, hw1 = pix1 % IMG;
    const int pb0 = (n0 * PIMG + (hw0 / 56) * 58 + (hw0 % 56)) * 128 + lcol;
    const int pb1 = (n1 * PIMG + (hw1 / 56) * 58 + (hw1 % 56)) * 128 + lcol;

    _Float16* AsW = As + wv * 512;  // wave-uniform LDS staging base (1KB/wave)
    _Float16* BsW = Bs + wv * 512;

    floatx4 acc[4][4] = {};

    for (int rs = 0; rs < 9; ++rs) {
        const _Float16* wg = wq + rs * (256 * 128);
        const _Float16* xg = xp + ((rs / 3) * 58 + (rs % 3)) * 128;   // tap shift (r*58+s)*128
        #pragma unroll 1
        for (int cc = 0; cc < 4; ++cc) {
            const int co = cc * 32;
            __builtin_amdgcn_global_load_lds((__attribute__((address_space(1))) void*)(wg + aoff0 + co),
                                             (__attribute__((address_space(3))) void*)(AsW), 16, 0, 0);
            __builtin_amdgcn_global_load_lds((__attribute__((address_space(1))) void*)(wg + aoff1 + co),
                                             (__attribute__((address_space(3))) void*)(AsW + 2048), 16, 0, 0);
            __builtin_amdgcn_global_load_lds((__attribute__((address_space(1))) void*)(xg + pb0 + co),
                                             (__attribute__((address_space(3))) void*)(BsW), 16, 0, 0);
            __builtin_amdgcn_global_load_lds((__attribute__((address_space(1))) void*)(xg + pb1 + co),
                                             (__attribute__((address_space(3))) void*)(BsW + 2048), 16, 0, 0);
            __syncthreads();   // compiler emits s_waitcnt vmcnt(0) before s_barrier

            half8 af[4], bf[4];
            const int ar = wm * 64 + (l & 15);
            const int br = wn * 64 + (l & 15);
            const int kq = (l >> 4) * 8;
            #pragma unroll
            for (int mi = 0; mi < 4; ++mi)
                af[mi] = *(const half8*)(As + (ar + mi * 16) * 32 + kq);
            #pragma unroll
            for (int ni = 0; ni < 4; ++ni)
                bf[ni] = *(const half8*)(Bs + (br + ni * 16) * 32 + kq);
            #pragma unroll
            for (int mi = 0; mi < 4; ++mi)
                #pragma unroll
                for (int ni = 0; ni < 4; ++ni)
                    acc[mi][ni] = __builtin_amdgcn_mfma_f32_16x16x32_f16(af[mi], bf[ni], acc[mi][ni], 0, 0, 0);
            __syncthreads();
        }
    }

    // epilogue: D[row=(l>>4)*4+reg = filter][col=l&15 = pixel]; pixel-contiguous stores
    #pragma unroll
    for (int mi = 0; mi < 4; ++mi) {
        const int kb = by * 128 + wm * 64 + mi * 16 + (l >> 4) * 4;
        #pragma unroll
        for (int rg = 0; rg < 4; ++rg) {
            const int k = kb + rg;
            const float bq = rintf(b[k] * 128.0f);
            #pragma unroll
            for (int ni = 0; ni < 4; ++ni) {
                const int pix = bx * 128 + wn * 64 + ni * 16 + (l & 15);
                const int n  = pix / IMG;
                const int pr = pix - n * IMG;
                out[((long)n * 256 + k) * IMG + pr] = acc[mi][ni][rg] * (1.0f / 128.0f) + bq;
            }
        }
    }
}

// ---------------- fallback (ws too small): direct conv, correct but slow ----------------
__global__ void conv_fallback_kernel(const float* __restrict__ x, const float* __restrict__ W,
                                     const float* __restrict__ b, float* __restrict__ out)
{
    __shared__ float wsm[1152];
    const int k = blockIdx.y;
    for (int i = threadIdx.x; i < 1152; i += 256)
        wsm[i] = rintf(W[k * 1152 + i] * 128.0f);
    __syncthreads();
    const int pix = blockIdx.x * 256 + threadIdx.x;   // 392*256 = 100352 exact
    const int n = pix / IMG, hw = pix % IMG;
    const int h = hw / 56, w = hw % 56;
    float acc = 0.0f;
    for (int c = 0; c < 128; ++c) {
        const float* xr = x + ((n * 128 + c) * 56) * 56;
        const float* wr = wsm + c * 9;
        #pragma unroll
        for (int r = 0; r < 3; ++r) {
            const int hh = h + r - 1;
            if ((unsigned)hh >= 56u) continue;
            #pragma unroll
            for (int s = 0; s < 3; ++s) {
                const int ww = w + s - 1;
                if ((unsigned)ww >= 56u) continue;
                acc += xr[hh * 56 + ww] * wr[r * 3 + s];
            }
        }
    }
    out[((long)n * 256 + k) * IMG + hw] = acc * (1.0f / 128.0f) + rintf(b[k] * 128.0f);
}

extern "C" void kernel_launch(void* const* d_in, const int* in_sizes, int n_in,
                              void* d_out, int out_size, void* d_ws, size_t ws_size,
                              hipStream_t stream) {
    const float* x = (const float*)d_in[0];
    const float* W = (const float*)d_in[1];
    const float* b = (const float*)d_in[2];
    float* out = (float*)d_out;

    const size_t need = (size_t)XP_ELEMS * 2 + (size_t)WQ_ELEMS * 2;   // 28,147,712 B
    if (ws_size >= need) {
        _Float16* xp = (_Float16*)d_ws;
        _Float16* wq = xp + XP_ELEMS;   // byte offset 27,557,888 (16B-aligned)
        pad_x_kernel<<<XP_ELEMS / 256, 256, 0, stream>>>(x, xp);
        quant_w_kernel<<<WQ_ELEMS / 256, 256, 0, stream>>>(W, wq);
        conv_mfma_kernel<<<dim3(784, 2), 256, 0, stream>>>(xp, wq, b, out);
    } else {
        conv_fallback_kernel<<<dim3(392, 256), 256, 0, stream>>>(x, W, b, out);
    }
}

// Round 2
// 225.700 us; speedup vs baseline: 1.1997x; 1.1997x over previous
//
#include <hip/hip_runtime.h>

typedef _Float16 half8 __attribute__((ext_vector_type(8)));
typedef float floatx4 __attribute__((ext_vector_type(4)));

#define IMG   3136      // 56*56
#define PIMG  3364      // 58*58
#define XP_ELEMS (32 * 58 * 58 * 128)   // 13,778,944 fp16
#define WQ_ELEMS (9 * 256 * 128)        // 294,912 fp16

// ---------------- pre-pass: x NCHW fp32 -> zero-padded NHWC fp16 ----------------
// grid (58, 32): blockIdx.x = padded row hh, blockIdx.y = n. 256 threads.
// Coalesced both sides via LDS transpose tile [128 c][56 w], stride 57 halves.
__global__ __launch_bounds__(256) void pad_x_kernel(const float* __restrict__ x,
                                                    _Float16* __restrict__ xp) {
    const int hh = blockIdx.x;          // 0..57
    const int n  = blockIdx.y;
    const int t  = threadIdx.x;
    _Float16* rowbase = xp + ((long)(n * 58 + hh) * 58) * 128;   // 58*128 halves

    if (hh == 0 || hh == 57) {
        // border row: 58*128 = 7424 halves = 928 chunks of 8
        #pragma unroll
        for (int i = 0; i < 4; ++i) {
            int idx = i * 256 + t;
            if (idx < 928) *(half8*)(rowbase + idx * 8) = (half8)(_Float16)0.0f;
        }
        return;
    }

    __shared__ _Float16 tile[128 * 57];     // stride 57: phase-2 column reads ~conflict-free
    const int h = hh - 1;

    // phase 1: 128 rows x 14 float4 = 1792 loads, coalesced
    #pragma unroll
    for (int p = 0; p < 7; ++p) {
        int idx = p * 256 + t;              // exact: 7*256 = 1792
        int c   = idx / 14;
        int w4  = (idx % 14) * 4;
        const float4 v = *(const float4*)(x + ((long)(n * 128 + c) * 56 + h) * 56 + w4);
        _Float16* d = tile + c * 57 + w4;
        d[0] = (_Float16)v.x; d[1] = (_Float16)v.y;
        d[2] = (_Float16)v.z; d[3] = (_Float16)v.w;
    }
    __syncthreads();

    // phase 2: 56 ww x 16 c-chunks = 896 half8 stores, coalesced
    #pragma unroll
    for (int p = 0; p < 4; ++p) {
        int idx = p * 256 + t;
        if (idx < 896) {
            int ww = idx >> 4;
            int c0 = (idx & 15) * 8;
            half8 v;
            #pragma unroll
            for (int j = 0; j < 8; ++j) v[j] = tile[(c0 + j) * 57 + ww];
            *(half8*)(rowbase + (ww + 1) * 128 + c0) = v;
        }
    }
    // zero columns ww = 0 and ww = 57
    if (t < 32) {
        int ww = (t >> 4) ? 57 : 0;
        int c0 = (t & 15) * 8;
        *(half8*)(rowbase + ww * 128 + c0) = (half8)(_Float16)0.0f;
    }
}

// ---------------- pre-pass: W[k][c][r][s] fp32 -> round(W*128) fp16 [rs][k][c] ----------------
__global__ void quant_w_kernel(const float* __restrict__ W, _Float16* __restrict__ wq) {
    int t = blockIdx.x * 256 + threadIdx.x;     // exact: 1152 * 256 = WQ_ELEMS
    int c  = t & 127;
    int k  = (t >> 7) & 255;
    int rs = t >> 15;
    wq[t] = (_Float16)rintf(W[(k * 128 + c) * 9 + rs] * 128.0f);
}

// ---------------- main: implicit GEMM, M=filters(256), N=pixels(100352), K=1152 ----------------
// block: 256 thr (4 waves, 2x2), tile 128x128, BK=32, mfma 16x16x32 f16
// LDS layout XOR-swizzled at 16B-chunk granularity: chunk (r,c) stored at (r, c ^ ((r>>1)&3))
// so fragment reads spread across all 8 bank groups (was 2 -> 7.2M conflict cycles).
__global__ __launch_bounds__(256) void conv_mfma_kernel(
    const _Float16* __restrict__ xp, const _Float16* __restrict__ wq,
    const float* __restrict__ b, float* __restrict__ out)
{
    __shared__ __align__(16) _Float16 smem[8192];   // A: [0,4096) halves, B: [4096,8192)
    _Float16* As = smem;            // [128 filt rows][32 c] 64B rows
    _Float16* Bs = smem + 4096;     // [128 pix rows][32 c]

    const int tid = threadIdx.x;
    const int l   = tid & 63;
    const int wv  = tid >> 6;
    const int wm  = wv & 1;         // filter half of tile
    const int wn  = wv >> 1;        // pixel half of tile
    const int bx  = blockIdx.x;     // pixel tile 0..783
    const int by  = blockIdx.y;     // filter tile 0..1

    // staging: lane l -> LDS chunk (r = wv*16 + (l>>2), c' = l&3); it must hold
    // global chunk c = c' ^ f(r), f(r) = (r>>1)&3 = (l>>3)&3 (wave-uniform)
    const int lrow = l >> 2;
    const int lcol = (((l & 3) ^ ((l >> 3) & 3))) * 8;

    // A (weights) element offsets
    const int kf0   = by * 128 + wv * 16 + lrow;
    const int aoff0 = kf0 * 128 + lcol;
    const int aoff1 = aoff0 + 64 * 128;

    // B (pixels): decode pixel -> padded-buffer base offset
    const int pix0 = bx * 128 + wv * 16 + lrow;
    const int pix1 = pix0 + 64;
    const int n0 = pix0 / IMG, hw0 = pix0 % IMG;
    const int n1 = pix1 / IMG, hw1 = pix1 % IMG;
    const int pb0 = (n0 * PIMG + (hw0 / 56) * 58 + (hw0 % 56)) * 128 + lcol;
    const int pb1 = (n1 * PIMG + (hw1 / 56) * 58 + (hw1 % 56)) * 128 + lcol;

    _Float16* AsW = As + wv * 512;  // wave-uniform LDS staging base (1KB/wave)
    _Float16* BsW = Bs + wv * 512;

    floatx4 acc[4][4] = {};

    for (int rs = 0; rs < 9; ++rs) {
        const _Float16* wg = wq + rs * (256 * 128);
        const _Float16* xg = xp + ((rs / 3) * 58 + (rs % 3)) * 128;   // tap shift (r*58+s)*128
        #pragma unroll 1
        for (int cc = 0; cc < 4; ++cc) {
            const int co = cc * 32;
            __builtin_amdgcn_global_load_lds((__attribute__((address_space(1))) void*)(wg + aoff0 + co),
                                             (__attribute__((address_space(3))) void*)(AsW), 16, 0, 0);
            __builtin_amdgcn_global_load_lds((__attribute__((address_space(1))) void*)(wg + aoff1 + co),
                                             (__attribute__((address_space(3))) void*)(AsW + 2048), 16, 0, 0);
            __builtin_amdgcn_global_load_lds((__attribute__((address_space(1))) void*)(xg + pb0 + co),
                                             (__attribute__((address_space(3))) void*)(BsW), 16, 0, 0);
            __builtin_amdgcn_global_load_lds((__attribute__((address_space(1))) void*)(xg + pb1 + co),
                                             (__attribute__((address_space(3))) void*)(BsW + 2048), 16, 0, 0);
            __syncthreads();

            half8 af[4], bf[4];
            const int ar = wm * 64 + (l & 15);
            const int br = wn * 64 + (l & 15);
            // read global chunk q = l>>4 of row: LDS chunk c' = q ^ f(row),
            // f(row) = (row>>1)&3 = (l>>1)&3 (mi/wm-uniform)
            const int kq = (((l >> 4) ^ ((l >> 1) & 3))) * 8;
            #pragma unroll
            for (int mi = 0; mi < 4; ++mi)
                af[mi] = *(const half8*)(As + (ar + mi * 16) * 32 + kq);
            #pragma unroll
            for (int ni = 0; ni < 4; ++ni)
                bf[ni] = *(const half8*)(Bs + (br + ni * 16) * 32 + kq);
            #pragma unroll
            for (int mi = 0; mi < 4; ++mi)
                #pragma unroll
                for (int ni = 0; ni < 4; ++ni)
                    acc[mi][ni] = __builtin_amdgcn_mfma_f32_16x16x32_f16(af[mi], bf[ni], acc[mi][ni], 0, 0, 0);
            __syncthreads();
        }
    }

    // epilogue: D[row=(l>>4)*4+reg = filter][col=l&15 = pixel]; pixel-contiguous stores
    #pragma unroll
    for (int mi = 0; mi < 4; ++mi) {
        const int kb = by * 128 + wm * 64 + mi * 16 + (l >> 4) * 4;
        #pragma unroll
        for (int rg = 0; rg < 4; ++rg) {
            const int k = kb + rg;
            const float bq = rintf(b[k] * 128.0f);
            #pragma unroll
            for (int ni = 0; ni < 4; ++ni) {
                const int pix = bx * 128 + wn * 64 + ni * 16 + (l & 15);
                const int n  = pix / IMG;
                const int pr = pix - n * IMG;
                out[((long)n * 256 + k) * IMG + pr] = acc[mi][ni][rg] * (1.0f / 128.0f) + bq;
            }
        }
    }
}

// ---------------- fallback (ws too small): direct conv, correct but slow ----------------
__global__ void conv_fallback_kernel(const float* __restrict__ x, const float* __restrict__ W,
                                     const float* __restrict__ b, float* __restrict__ out)
{
    __shared__ float wsm[1152];
    const int k = blockIdx.y;
    for (int i = threadIdx.x; i < 1152; i += 256)
        wsm[i] = rintf(W[k * 1152 + i] * 128.0f);
    __syncthreads();
    const int pix = blockIdx.x * 256 + threadIdx.x;   // 392*256 = 100352 exact
    const int n = pix / IMG, hw = pix % IMG;
    const int h = hw / 56, w = hw % 56;
    float acc = 0.0f;
    for (int c = 0; c < 128; ++c) {
        const float* xr = x + ((n * 128 + c) * 56) * 56;
        const float* wr = wsm + c * 9;
        #pragma unroll
        for (int r = 0; r < 3; ++r) {
            const int hh = h + r - 1;
            if ((unsigned)hh >= 56u) continue;
            #pragma unroll
            for (int s = 0; s < 3; ++s) {
                const int ww = w + s - 1;
                if ((unsigned)ww >= 56u) continue;
                acc += xr[hh * 56 + ww] * wr[r * 3 + s];
            }
        }
    }
    out[((long)n * 256 + k) * IMG + hw] = acc * (1.0f / 128.0f) + rintf(b[k] * 128.0f);
}

extern "C" void kernel_launch(void* const* d_in, const int* in_sizes, int n_in,
                              void* d_out, int out_size, void* d_ws, size_t ws_size,
                              hipStream_t stream) {
    const float* x = (const float*)d_in[0];
    const float* W = (const float*)d_in[1];
    const float* b = (const float*)d_in[2];
    float* out = (float*)d_out;

    const size_t need = (size_t)XP_ELEMS * 2 + (size_t)WQ_ELEMS * 2;   // 28,147,712 B
    if (ws_size >= need) {
        _Float16* xp = (_Float16*)d_ws;
        _Float16* wq = xp + XP_ELEMS;   // byte offset 27,557,888 (16B-aligned)
        pad_x_kernel<<<dim3(58, 32), 256, 0, stream>>>(x, xp);
        quant_w_kernel<<<WQ_ELEMS / 256, 256, 0, stream>>>(W, wq);
        conv_mfma_kernel<<<dim3(784, 2), 256, 0, stream>>>(xp, wq, b, out);
    } else {
        conv_fallback_kernel<<<dim3(392, 256), 256, 0, stream>>>(x, W, b, out);
    }
}

// Round 3
// 212.896 us; speedup vs baseline: 1.2719x; 1.0601x over previous
//
#include <hip/hip_runtime.h>

typedef _Float16 half8 __attribute__((ext_vector_type(8)));
typedef float floatx4 __attribute__((ext_vector_type(4)));

#define IMG   3136      // 56*56
#define PIMG  3364      // 58*58
#define XP_ELEMS (32 * 58 * 58 * 128)   // 13,778,944 fp16
#define WQ_ELEMS (9 * 256 * 128)        // 294,912 fp16

#define AS1 __attribute__((address_space(1)))
#define AS3 __attribute__((address_space(3)))

// ---------------- pre-pass: x NCHW fp32 -> zero-padded NHWC fp16 (unchanged, ~15-20us) ----------
__global__ __launch_bounds__(256) void pad_x_kernel(const float* __restrict__ x,
                                                    _Float16* __restrict__ xp) {
    const int hh = blockIdx.x;          // 0..57
    const int n  = blockIdx.y;
    const int t  = threadIdx.x;
    _Float16* rowbase = xp + ((long)(n * 58 + hh) * 58) * 128;

    if (hh == 0 || hh == 57) {
        #pragma unroll
        for (int i = 0; i < 4; ++i) {
            int idx = i * 256 + t;
            if (idx < 928) *(half8*)(rowbase + idx * 8) = (half8)(_Float16)0.0f;
        }
        return;
    }

    __shared__ _Float16 tile[128 * 57];
    const int h = hh - 1;

    #pragma unroll
    for (int p = 0; p < 7; ++p) {
        int idx = p * 256 + t;              // 7*256 = 1792
        int c   = idx / 14;
        int w4  = (idx % 14) * 4;
        const float4 v = *(const float4*)(x + ((long)(n * 128 + c) * 56 + h) * 56 + w4);
        _Float16* d = tile + c * 57 + w4;
        d[0] = (_Float16)v.x; d[1] = (_Float16)v.y;
        d[2] = (_Float16)v.z; d[3] = (_Float16)v.w;
    }
    __syncthreads();

    #pragma unroll
    for (int p = 0; p < 4; ++p) {
        int idx = p * 256 + t;
        if (idx < 896) {
            int ww = idx >> 4;
            int c0 = (idx & 15) * 8;
            half8 v;
            #pragma unroll
            for (int j = 0; j < 8; ++j) v[j] = tile[(c0 + j) * 57 + ww];
            *(half8*)(rowbase + (ww + 1) * 128 + c0) = v;
        }
    }
    if (t < 32) {
        int ww = (t >> 4) ? 57 : 0;
        int c0 = (t & 15) * 8;
        *(half8*)(rowbase + ww * 128 + c0) = (half8)(_Float16)0.0f;
    }
}

// ---------------- pre-pass: W[k][c][r][s] fp32 -> round(W*128) fp16 [rs][k][c] ----------------
__global__ void quant_w_kernel(const float* __restrict__ W, _Float16* __restrict__ wq) {
    int t = blockIdx.x * 256 + threadIdx.x;     // 1152 * 256 = WQ_ELEMS
    int c  = t & 127;
    int k  = (t >> 7) & 255;
    int rs = t >> 15;
    wq[t] = (_Float16)rintf(W[(k * 128 + c) * 9 + rs] * 128.0f);
}

// ---------------- main: implicit GEMM, M=256, N=100352, K=1152 ----------------
// Double-buffered LDS + raw s_waitcnt vmcnt(4)/s_barrier: stage s+1's loads stay
// in flight across the barrier while stage s computes (m139/AITER-style K-loop;
// __syncthreads' forced vmcnt(0) drain was the ~60% stall at MfmaUtil=24%).
// 36 K-steps total: step t = (rs<<2)|cc, tap rs in [0,9), c-chunk cc in [0,4).
__global__ __launch_bounds__(256) void conv_mfma_kernel(
    const _Float16* __restrict__ xp, const _Float16* __restrict__ wq,
    const float* __restrict__ b, float* __restrict__ out)
{
    __shared__ __align__(16) _Float16 smem[16384];  // 2 x (A 4096 + B 4096) halves = 32 KB

    const int tid = threadIdx.x;
    const int l   = tid & 63;
    const int wv  = tid >> 6;
    const int wm  = wv & 1;         // filter half of tile
    const int wn  = wv >> 1;        // pixel half of tile
    const int bx  = blockIdx.x;     // pixel tile 0..783
    const int by  = blockIdx.y;     // filter tile 0..1

    // staging: lane l -> LDS chunk (r = wv*16 + (l>>2), c' = l&3) holding global
    // chunk c = c' ^ ((l>>3)&3)  (XOR swizzle, verified 0 conflicts in R2)
    const int lrow = l >> 2;
    const int lcol = ((l & 3) ^ ((l >> 3) & 3)) * 8;

    const int aoff0 = (by * 128 + wv * 16 + lrow) * 128 + lcol;
    const int aoff1 = aoff0 + 64 * 128;

    const int pix0 = bx * 128 + wv * 16 + lrow;
    const int pix1 = pix0 + 64;
    const int n0 = pix0 / IMG, hw0 = pix0 % IMG;
    const int n1 = pix1 / IMG, hw1 = pix1 % IMG;
    const int pb0 = (n0 * PIMG + (hw0 / 56) * 58 + (hw0 % 56)) * 128 + lcol;
    const int pb1 = (n1 * PIMG + (hw1 / 56) * 58 + (hw1 % 56)) * 128 + lcol;

    const int stageoff = wv * 512;  // 1KB staging region per wave

    floatx4 acc[4][4] = {};

    // issue the 4 global_load_lds for K-step t into buffer pbuf
    auto issue = [&](int t, int pbuf) {
        const int rs = t >> 2;
        const int cc = t & 3;
        const int r  = (rs * 11) >> 5;          // rs/3 for rs in [0,9)
        const int s2 = rs - r * 3;
        const _Float16* wg = wq + rs * (256 * 128);
        const _Float16* xg = xp + (r * 58 + s2) * 128;
        const int co = cc * 32;
        _Float16* A = smem + pbuf * 8192 + stageoff;
        _Float16* B = smem + pbuf * 8192 + 4096 + stageoff;
        __builtin_amdgcn_global_load_lds((AS1 void*)(wg + aoff0 + co), (AS3 void*)A,          16, 0, 0);
        __builtin_amdgcn_global_load_lds((AS1 void*)(wg + aoff1 + co), (AS3 void*)(A + 2048), 16, 0, 0);
        __builtin_amdgcn_global_load_lds((AS1 void*)(xg + pb0  + co), (AS3 void*)B,          16, 0, 0);
        __builtin_amdgcn_global_load_lds((AS1 void*)(xg + pb1  + co), (AS3 void*)(B + 2048), 16, 0, 0);
    };

    const int ar = wm * 64 + (l & 15);
    const int br = wn * 64 + (l & 15);
    const int kq = ((l >> 4) ^ ((l >> 1) & 3)) * 8;   // read-side swizzle

    auto compute = [&](int pbuf) {
        const _Float16* As = smem + pbuf * 8192;
        const _Float16* Bs = As + 4096;
        half8 af[4], bf[4];
        #pragma unroll
        for (int mi = 0; mi < 4; ++mi)
            af[mi] = *(const half8*)(As + (ar + mi * 16) * 32 + kq);
        #pragma unroll
        for (int ni = 0; ni < 4; ++ni)
            bf[ni] = *(const half8*)(Bs + (br + ni * 16) * 32 + kq);
        #pragma unroll
        for (int mi = 0; mi < 4; ++mi)
            #pragma unroll
            for (int ni = 0; ni < 4; ++ni)
                acc[mi][ni] = __builtin_amdgcn_mfma_f32_16x16x32_f16(af[mi], bf[ni], acc[mi][ni], 0, 0, 0);
    };

    issue(0, 0);
    #pragma unroll 2
    for (int s = 0; s < 35; ++s) {
        issue(s + 1, (s + 1) & 1);
        // wait for step s's 4 loads (oldest; vmcnt retires in issue order),
        // leaving step s+1's 4 in flight across the barrier
        asm volatile("s_waitcnt vmcnt(4)" ::: "memory");
        asm volatile("s_barrier" ::: "memory");
        compute(s & 1);
        asm volatile("s_barrier" ::: "memory");   // readers done before s+2 overwrites
    }
    asm volatile("s_waitcnt vmcnt(0)" ::: "memory");
    asm volatile("s_barrier" ::: "memory");
    compute(1);   // step 35

    // epilogue: D[row=(l>>4)*4+reg = filter][col=l&15 = pixel]
    #pragma unroll
    for (int mi = 0; mi < 4; ++mi) {
        const int kb = by * 128 + wm * 64 + mi * 16 + (l >> 4) * 4;
        #pragma unroll
        for (int rg = 0; rg < 4; ++rg) {
            const int k = kb + rg;
            const float bq = rintf(b[k] * 128.0f);
            #pragma unroll
            for (int ni = 0; ni < 4; ++ni) {
                const int pix = bx * 128 + wn * 64 + ni * 16 + (l & 15);
                const int n  = pix / IMG;
                const int pr = pix - n * IMG;
                out[((long)n * 256 + k) * IMG + pr] = acc[mi][ni][rg] * (1.0f / 128.0f) + bq;
            }
        }
    }
}

// ---------------- fallback (ws too small): direct conv, correct but slow ----------------
__global__ void conv_fallback_kernel(const float* __restrict__ x, const float* __restrict__ W,
                                     const float* __restrict__ b, float* __restrict__ out)
{
    __shared__ float wsm[1152];
    const int k = blockIdx.y;
    for (int i = threadIdx.x; i < 1152; i += 256)
        wsm[i] = rintf(W[k * 1152 + i] * 128.0f);
    __syncthreads();
    const int pix = blockIdx.x * 256 + threadIdx.x;
    const int n = pix / IMG, hw = pix % IMG;
    const int h = hw / 56, w = hw % 56;
    float acc = 0.0f;
    for (int c = 0; c < 128; ++c) {
        const float* xr = x + ((n * 128 + c) * 56) * 56;
        const float* wr = wsm + c * 9;
        #pragma unroll
        for (int r = 0; r < 3; ++r) {
            const int hh = h + r - 1;
            if ((unsigned)hh >= 56u) continue;
            #pragma unroll
            for (int s = 0; s < 3; ++s) {
                const int ww = w + s - 1;
                if ((unsigned)ww >= 56u) continue;
                acc += xr[hh * 56 + ww] * wr[r * 3 + s];
            }
        }
    }
    out[((long)n * 256 + k) * IMG + hw] = acc * (1.0f / 128.0f) + rintf(b[k] * 128.0f);
}

extern "C" void kernel_launch(void* const* d_in, const int* in_sizes, int n_in,
                              void* d_out, int out_size, void* d_ws, size_t ws_size,
                              hipStream_t stream) {
    const float* x = (const float*)d_in[0];
    const float* W = (const float*)d_in[1];
    const float* b = (const float*)d_in[2];
    float* out = (float*)d_out;

    const size_t need = (size_t)XP_ELEMS * 2 + (size_t)WQ_ELEMS * 2;   // 28,147,712 B
    if (ws_size >= need) {
        _Float16* xp = (_Float16*)d_ws;
        _Float16* wq = xp + XP_ELEMS;
        pad_x_kernel<<<dim3(58, 32), 256, 0, stream>>>(x, xp);
        quant_w_kernel<<<WQ_ELEMS / 256, 256, 0, stream>>>(W, wq);
        conv_mfma_kernel<<<dim3(784, 2), 256, 0, stream>>>(xp, wq, b, out);
    } else {
        conv_fallback_kernel<<<dim3(392, 256), 256, 0, stream>>>(x, W, b, out);
    }
}